// Round 1
// 1188.728 us; speedup vs baseline: 1.1073x; 1.1073x over previous
//
#include <hip/hip_runtime.h>
#include <math.h>

// GatedDeltaNet forward, MI355X round 5: prep_chunks rebuilt —
//   * A = K K^T and Qd = Q K^T via bf16 MFMA (same bf16 inputs as the old
//     fp32 path, fp32 accum -> numerically equivalent), kills the scalar
//     matmul phase and its stride-128 bank conflicts.
//   * Triangular inversion: per-wave 16x16 diagonal-block inverse in
//     registers + 3 blocked forward-substitution stages (shfl-redistributed),
//     replacing the 63-iteration / 126-barrier serial loop. All fp32.
//   * Wm/U kept as fp32 register tiles (T stays fp32 -> no extra rounding).
// B=2 L=4096 D=2048 H=16 Dh=128 C=64 KW=4
#define B_   2
#define L_   4096
#define D_   2048
#define H_   16
#define DH   128
#define CH   64
#define NCH  64
#define HD   2048
#define BH   32
#define BHL  131072
#define PSZ  16777216ull

typedef unsigned short u16;
typedef __attribute__((ext_vector_type(8))) short bf16x8;
typedef __attribute__((ext_vector_type(4))) float f32x4;
#define MFMA16(a, b, c) __builtin_amdgcn_mfma_f32_16x16x32_bf16(a, b, c, 0, 0, 0)

static __device__ __forceinline__ float sigm(float x) { return 1.0f / (1.0f + expf(-x)); }

static __device__ __forceinline__ float b2f(u16 u) {
    union { float f; unsigned int i; } v; v.i = ((unsigned int)u) << 16; return v.f;
}
static __device__ __forceinline__ u16 f2b(float f) {
    union { float f; unsigned int i; } v; v.f = f;
    unsigned int r = v.i + 0x7fffu + ((v.i >> 16) & 1u);
    return (u16)(r >> 16);
}
static __device__ __forceinline__ void b8ld(const u16* p, float* d) {
    uint4 u = *(const uint4*)p;
    d[0] = b2f((u16)(u.x & 0xffff)); d[1] = b2f((u16)(u.x >> 16));
    d[2] = b2f((u16)(u.y & 0xffff)); d[3] = b2f((u16)(u.y >> 16));
    d[4] = b2f((u16)(u.z & 0xffff)); d[5] = b2f((u16)(u.z >> 16));
    d[6] = b2f((u16)(u.w & 0xffff)); d[7] = b2f((u16)(u.w >> 16));
}
static __device__ __forceinline__ void b8st(const float* s, u16* p) {
    uint4 u;
    u.x = (unsigned)f2b(s[0]) | ((unsigned)f2b(s[1]) << 16);
    u.y = (unsigned)f2b(s[2]) | ((unsigned)f2b(s[3]) << 16);
    u.z = (unsigned)f2b(s[4]) | ((unsigned)f2b(s[5]) << 16);
    u.w = (unsigned)f2b(s[6]) | ((unsigned)f2b(s[7]) << 16);
    *(uint4*)p = u;
}
static __device__ __forceinline__ float4 ldA4(const u16* p) {
    ushort4 u = *(const ushort4*)p;
    float4 f; f.x = b2f(u.x); f.y = b2f(u.y); f.z = b2f(u.z); f.w = b2f(u.w); return f;
}
static __device__ __forceinline__ void cstore(float* p, float v) { *p = v; }
static __device__ __forceinline__ void cstore(u16* p, float v) { *p = f2b(v); }

// async 16B global -> LDS (dest = wave-uniform base + lane*16; our layout is
// lane-consecutive by construction)
static __device__ __forceinline__ void async16(const u16* g, u16* l) {
    __builtin_amdgcn_global_load_lds(
        (const __attribute__((address_space(1))) unsigned int*)g,
        (__attribute__((address_space(3))) unsigned int*)l, 16, 0, 0);
}

// fp32 -> bf16 bulk convert (n multiple of 8; one 8-elt group per thread)
__global__ __launch_bounds__(256) void cvt_f2b(const float* __restrict__ in,
                                               u16* __restrict__ out, int n8) {
    int i = blockIdx.x * 256 + threadIdx.x;
    if (i >= n8) return;
    float t[8];
    float4 a = *(const float4*)(in + (size_t)i * 8);
    float4 b = *(const float4*)(in + (size_t)i * 8 + 4);
    t[0] = a.x; t[1] = a.y; t[2] = a.z; t[3] = a.w;
    t[4] = b.x; t[5] = b.y; t[6] = b.z; t[7] = b.w;
    b8st(t, out + (size_t)i * 8);
}

// ---------------------------------------------------------------------------
// m97-style async MFMA GEMM: C[M,N] = A[M,K] @ B[N,K]^T, bf16 in, fp32 acc.
// 128x128 tile, BK=64, 4 waves (64x64 quadrant each, 4x4 16x16x32 tiles).
// LDS: unpadded 128x64 bf16 tiles, octets XOR-swizzled (slot c holds global
// octet (c&7)^(row&7)) so fragment ds_read_b128 is 2-way max (free).
// ---------------------------------------------------------------------------
template <typename TC>
__global__ __launch_bounds__(256) void gemm_bt_async(const u16* __restrict__ A,
                                                     const u16* __restrict__ Bm,
                                                     TC* __restrict__ Cm,
                                                     int M, int N, int K) {
    __shared__ __align__(16) u16 sA[128 * 64];
    __shared__ __align__(16) u16 sB[128 * 64];
    const int tid = threadIdx.x;
    const int w = tid >> 6, lane = tid & 63, lq = lane >> 4, ln = lane & 15;
    const int wm = w >> 1, wn = w & 1;
    const int mbase = blockIdx.y * 128, nbase = blockIdx.x * 128;

    f32x4 acc[4][4];
#pragma unroll
    for (int mt = 0; mt < 4; mt++)
#pragma unroll
        for (int nt = 0; nt < 4; nt++) acc[mt][nt] = (f32x4){0.f, 0.f, 0.f, 0.f};

    for (int k0 = 0; k0 < K; k0 += 64) {
#pragma unroll
        for (int j = 0; j < 4; j++) {
            int c = tid + 256 * j;                 // LDS chunk slot 0..1023
            int row = c >> 3;
            int oct = (c & 7) ^ (row & 7);         // swizzled source octet
            async16(A + (size_t)(mbase + row) * K + k0 + oct * 8, &sA[c * 8]);
            async16(Bm + (size_t)(nbase + row) * K + k0 + oct * 8, &sB[c * 8]);
        }
        __syncthreads();
#pragma unroll
        for (int ks = 0; ks < 2; ks++) {
            const int o = ks * 4 + lq;             // k-octet this quarter needs
            bf16x8 af[4], bfr[4];
#pragma unroll
            for (int mt = 0; mt < 4; mt++) {
                int m = wm * 64 + mt * 16 + ln;
                af[mt] = *(const bf16x8*)&sA[(m << 6) + ((o ^ (m & 7)) << 3)];
            }
#pragma unroll
            for (int nt = 0; nt < 4; nt++) {
                int nn = wn * 64 + nt * 16 + ln;
                bfr[nt] = *(const bf16x8*)&sB[(nn << 6) + ((o ^ (nn & 7)) << 3)];
            }
#pragma unroll
            for (int mt = 0; mt < 4; mt++)
#pragma unroll
                for (int nt = 0; nt < 4; nt++)
                    acc[mt][nt] = MFMA16(af[mt], bfr[nt], acc[mt][nt]);
        }
        __syncthreads();
    }
#pragma unroll
    for (int mt = 0; mt < 4; mt++)
#pragma unroll
        for (int nt = 0; nt < 4; nt++) {
            int col = nbase + wn * 64 + nt * 16 + ln;
#pragma unroll
            for (int r = 0; r < 4; r++) {
                int row = mbase + wm * 64 + mt * 16 + lq * 4 + r;
                cstore(Cm + (size_t)row * N + col, acc[mt][nt][r]);
            }
        }
}

// ---------------------------------------------------------------------------
// Causal depthwise conv (KW=4) + SiLU + optional L2 norm over Dh.
// ---------------------------------------------------------------------------
__global__ __launch_bounds__(256) void conv_silu_norm(const u16* __restrict__ pre,
                                                      const float* __restrict__ w,
                                                      u16* __restrict__ out, int mode) {
    int wid = blockIdx.x * 4 + (threadIdx.x >> 6);
    int lane = threadIdx.x & 63;
    int l = wid & (L_ - 1);
    int bh = wid >> 12;
    int b = bh >> 4, h = bh & 15;

    float vals[2];
    float sumsq = 0.0f;
#pragma unroll
    for (int s = 0; s < 2; s++) {
        int d = lane + 64 * s;
        int c = h * DH + d;
        const u16* col = pre + (size_t)b * L_ * HD + c;
        float acc = 0.0f;
        if (l >= 3) {
            acc = w[c * 4 + 0] * b2f(col[(size_t)(l - 3) * HD]) +
                  w[c * 4 + 1] * b2f(col[(size_t)(l - 2) * HD]) +
                  w[c * 4 + 2] * b2f(col[(size_t)(l - 1) * HD]) +
                  w[c * 4 + 3] * b2f(col[(size_t)l * HD]);
        } else {
#pragma unroll
            for (int j = 0; j < 4; j++) {
                int ll = l - 3 + j;
                if (ll >= 0) acc += w[c * 4 + j] * b2f(col[(size_t)ll * HD]);
            }
        }
        float y = acc * sigm(acc);
        vals[s] = y;
        sumsq += y * y;
    }
    if (mode < 2) {
#pragma unroll
        for (int m = 32; m >= 1; m >>= 1) sumsq += __shfl_xor(sumsq, m, 64);
        float scale = 1.0f / fmaxf(sqrtf(sumsq), 1e-12f);
        if (mode == 0) scale *= 0.08838834764831843f;
        vals[0] *= scale;
        vals[1] *= scale;
    }
    u16* o = out + ((size_t)bh * L_ + l) * DH;
    o[lane] = f2b(vals[0]);
    o[lane + 64] = f2b(vals[1]);
}

__global__ __launch_bounds__(64) void proj_small(const float* __restrict__ x,
                                                 const float* __restrict__ Wb,
                                                 const float* __restrict__ Wa,
                                                 float* __restrict__ bpre,
                                                 float* __restrict__ apre) {
    int row = blockIdx.x;
    int lane = threadIdx.x;
    const float* xr = x + (size_t)row * D_;
    float xv[32];
#pragma unroll
    for (int j = 0; j < 32; j++) xv[j] = xr[lane + 64 * j];
    for (int h = 0; h < 16; h++) {
        const float* wr = Wb + (size_t)h * D_;
        float acc = 0.0f;
#pragma unroll
        for (int j = 0; j < 32; j++) acc += xv[j] * wr[lane + 64 * j];
#pragma unroll
        for (int m = 32; m >= 1; m >>= 1) acc += __shfl_xor(acc, m, 64);
        if (lane == 0) bpre[(size_t)row * 16 + h] = acc;
    }
    for (int h = 0; h < 16; h++) {
        const float* wr = Wa + (size_t)h * D_;
        float acc = 0.0f;
#pragma unroll
        for (int j = 0; j < 32; j++) acc += xv[j] * wr[lane + 64 * j];
#pragma unroll
        for (int m = 32; m >= 1; m >>= 1) acc += __shfl_xor(acc, m, 64);
        if (lane == 0) apre[(size_t)row * 16 + h] = acc;
    }
}

__global__ __launch_bounds__(256) void beta_g_k(const float* __restrict__ bpre,
                                                const float* __restrict__ apre,
                                                const float* __restrict__ A_log,
                                                const float* __restrict__ dt_bias,
                                                float* __restrict__ beta, float* __restrict__ g) {
    int gi = blockIdx.x * 256 + threadIdx.x;
    int l = gi & (L_ - 1);
    int bh = gi >> 12;
    int b = bh >> 4, h = bh & 15;
    float bp = bpre[((size_t)b * L_ + l) * 16 + h];
    float ap = apre[((size_t)b * L_ + l) * 16 + h] + dt_bias[h];
    float sp = (ap > 20.0f) ? ap : log1pf(expf(ap));
    beta[(size_t)bh * L_ + l] = 1.0f / (1.0f + expf(-bp));
    g[(size_t)bh * L_ + l] = -expf(A_log[h]) * sp;
}

// ---------------------------------------------------------------------------
// Per-chunk prep (2048 blocks, 4 waves).
//   P0: prefetch Q frags (global), stage K -> LDS (stride 136), cumsum/γ.
//   P1: A = K K^T, Qd = Q K^T via bf16 MFMA; mask -> sA (fp32) / W2 (global).
//   P2a: per-wave register inversion of 16x16 diagonal blocks; scale q,k.
//   P2b: 3 blocked forward-substitution stages (shfl redistribution).
//   P3: Wm = T @ (βγK), U = T @ (βV) as fp32 register tiles (old code path,
//       now reading fp32 T from sT and bf16 K from sKb with on-the-fly scale).
// LDS = 52.5 KB -> 3 blocks/CU.
// ---------------------------------------------------------------------------
__global__ __launch_bounds__(256) void prep_chunks(u16* __restrict__ q, u16* __restrict__ k,
                                                   u16* __restrict__ v,
                                                   const float* __restrict__ beta,
                                                   const float* __restrict__ g,
                                                   u16* __restrict__ Wm, u16* __restrict__ W2,
                                                   float* __restrict__ gamC) {
    __shared__ __align__(16) u16 sKb[64 * 136];   // raw K (bf16), MFMA-friendly stride
    __shared__ __align__(16) float sA[64 * 65];   // masked A (strict lower, fp32)
    __shared__ __align__(16) float sT[64 * 68];   // T = A^{-1} (fp32, stride 68)
    __shared__ float sLg[CH], sGam[CH], sGcr[CH], sBeta[CH];

    const int cid = blockIdx.x;
    const int bh = cid >> 6, n = cid & 63;
    const int tid = threadIdx.x;
    const int w = tid >> 6, lane = tid & 63, lq = lane >> 4, ln = lane & 15;
    const size_t cbase = ((size_t)bh * L_ + (size_t)n * CH) * DH;
    u16* qw = q + cbase;
    u16* kw = k + cbase;
    u16* vc = v + cbase;

    // ---- P0: Q fragment prefetch + K staging + cumsum ----
    bf16x8 aQ[4];
    {
        const u16* qrow = qw + (size_t)(w * 16 + ln) * DH;
#pragma unroll
        for (int ks = 0; ks < 4; ks++)
            aQ[ks] = *(const bf16x8*)(qrow + ks * 32 + lq * 8);
    }
#pragma unroll
    for (int rep = 0; rep < 4; rep++) {
        int f = tid + 256 * rep;                   // 1024 chunks of 8 u16
        int row = f >> 4, c8 = (f & 15) * 8;
        *(uint4*)&sKb[row * 136 + c8] = *(const uint4*)(kw + (size_t)row * DH + c8);
    }
    if (tid < 64) {
        float lg = g[(size_t)bh * L_ + (size_t)n * CH + tid];
#pragma unroll
        for (int off = 1; off < 64; off <<= 1) {
            float u = __shfl_up(lg, off, 64);
            if (tid >= off) lg += u;
        }
        float lgC = __shfl(lg, 63, 64);
        sLg[tid] = lg;
        sGam[tid] = expf(lg);
        sGcr[tid] = expf(lgC - lg);
        sBeta[tid] = beta[(size_t)bh * L_ + (size_t)n * CH + tid];
        if (tid == 63) gamC[cid] = expf(lgC);
    }
    __syncthreads();

    // ---- P1: MFMA A/Qd + mask/write; zero sT ----
    {
        f32x4 accA[4], accQ[4];
#pragma unroll
        for (int nt = 0; nt < 4; nt++) {
            accA[nt] = (f32x4){0.f, 0.f, 0.f, 0.f};
            accQ[nt] = (f32x4){0.f, 0.f, 0.f, 0.f};
        }
#pragma unroll
        for (int ks = 0; ks < 4; ks++) {
            int k0 = ks * 32 + lq * 8;
            bf16x8 aK = *(const bf16x8*)&sKb[(w * 16 + ln) * 136 + k0];
#pragma unroll
            for (int nt = 0; nt < 4; nt++) {
                bf16x8 bK = *(const bf16x8*)&sKb[(nt * 16 + ln) * 136 + k0];
                accA[nt] = MFMA16(aK, bK, accA[nt]);
                accQ[nt] = MFMA16(aQ[ks], bK, accQ[nt]);
            }
        }
        for (int idx = tid; idx < 64 * 68; idx += 256) sT[idx] = 0.f;
        u16* w2c = W2 + (size_t)cid * CH * CH;
#pragma unroll
        for (int nt = 0; nt < 4; nt++) {
            int j = nt * 16 + ln;
            float lgj = sLg[j];
#pragma unroll
            for (int r = 0; r < 4; r++) {
                int i = w * 16 + lq * 4 + r;
                float dexp = expf(fminf(sLg[i] - lgj, 0.f));  // valid for j<=i; clamped else
                sA[i * 65 + j] = (j < i) ? sBeta[i] * dexp * accA[nt][r] : 0.f;
                w2c[i * CH + j] = f2b((j <= i) ? accQ[nt][r] * dexp : 0.f);
            }
        }
    }
    __syncthreads();

    // ---- P2a: per-wave diagonal 16x16 inversion (registers) + q/k scaling ----
    float colv[16];   // lane ln holds column ln of Dinv for wave w's block
    {
        const int i0 = w * 16;
        colv[0] = (ln == 0) ? 1.f : 0.f;
#pragma unroll
        for (int i = 1; i < 16; i++) {
            float acc = (ln == i) ? 1.f : 0.f;
#pragma unroll
            for (int kk = 0; kk < 15; kk++) {
                if (kk < i) acc -= sA[(i0 + i) * 65 + i0 + kk] * colv[kk];
            }
            colv[i] = acc;
        }
    }
#pragma unroll
    for (int rep = 0; rep < 4; rep++) {            // q *= γ, k *= γC/γ (global RMW)
        int f = tid + 256 * rep;
        int i = f >> 4, d8 = (f & 15) * 8;
        float tq[8], tk[8];
        b8ld(qw + (size_t)i * DH + d8, tq);
        b8ld(kw + (size_t)i * DH + d8, tk);
        float sq = sGam[i], sk2 = sGcr[i];
#pragma unroll
        for (int jj = 0; jj < 8; jj++) { tq[jj] *= sq; tk[jj] *= sk2; }
        b8st(tq, qw + (size_t)i * DH + d8);
        b8st(tk, kw + (size_t)i * DH + d8);
    }
    if (lq == 0) {
#pragma unroll
        for (int i = 0; i < 16; i++) sT[(w * 16 + i) * 68 + w * 16 + ln] = colv[i];
    }
    __syncthreads();

    // ---- P2b: blocked forward substitution, T_ij = -Dinv_i * sum A_ik T_kj ----
    auto trijob = [&](int bi, int bj) {
        float accv[4] = {0.f, 0.f, 0.f, 0.f};      // Ssum[lq*4+r][ln]
        for (int kb = bj; kb < bi; kb++) {
#pragma unroll
            for (int kk = 0; kk < 16; kk++) {
                float bv = sT[(kb * 16 + kk) * 68 + bj * 16 + ln];
#pragma unroll
                for (int r = 0; r < 4; r++)
                    accv[r] += sA[(bi * 16 + lq * 4 + r) * 65 + kb * 16 + kk] * bv;
            }
        }
        float xv[4] = {0.f, 0.f, 0.f, 0.f};
#pragma unroll
        for (int kk = 0; kk < 16; kk++) {
            // Ssum[kk][ln] lives in lane (kk>>2)*16+ln, register kk&3
            float bv = __shfl(accv[kk & 3], (kk >> 2) * 16 + ln, 64);
#pragma unroll
            for (int r = 0; r < 4; r++)
                xv[r] -= sT[(bi * 16 + lq * 4 + r) * 68 + bi * 16 + kk] * bv;
        }
#pragma unroll
        for (int r = 0; r < 4; r++)
            sT[(bi * 16 + lq * 4 + r) * 68 + bj * 16 + ln] = xv[r];
    };
    if (w < 3) trijob(w + 1, w);
    __syncthreads();
    if (w < 2) trijob(w + 2, w);
    __syncthreads();
    if (w == 0) trijob(3, 0);
    __syncthreads();

    // ---- P3: Wm = T @ (βγK), U = T @ (βV) — fp32 register tiles ----
    {
        int ib = tid >> 4, cb = tid & 15;
        int i0 = ib * 4, c0 = cb * 8;
        float accK[4][8], accV[4][8];
#pragma unroll
        for (int r = 0; r < 4; r++)
#pragma unroll
            for (int c = 0; c < 8; c++) { accK[r][c] = 0.0f; accV[r][c] = 0.0f; }
        for (int kk = 0; kk < CH; kk += 4) {
            float tr[4][4];
#pragma unroll
            for (int r = 0; r < 4; r++) {
                float4 t4 = *(const float4*)&sT[(i0 + r) * 68 + kk];
                tr[r][0] = t4.x; tr[r][1] = t4.y; tr[r][2] = t4.z; tr[r][3] = t4.w;
            }
#pragma unroll
            for (int s = 0; s < 4; s++) {
                int kks = kk + s;
                float va[8], ka[8];
                b8ld(vc + (size_t)kks * DH + c0, va);
                b8ld(&sKb[kks * 136 + c0], ka);
                float bv = sBeta[kks];
                float kf = bv * sGam[kks];
#pragma unroll
                for (int c = 0; c < 8; c++) { va[c] *= bv; ka[c] *= kf; }
#pragma unroll
                for (int r = 0; r < 4; r++) {
                    float t = tr[r][s];
#pragma unroll
                    for (int c = 0; c < 8; c++) {
                        accK[r][c] += t * ka[c];
                        accV[r][c] += t * va[c];
                    }
                }
            }
        }
        u16* wmc = Wm + (size_t)cid * CH * DH;
#pragma unroll
        for (int r = 0; r < 4; r++) b8st(&accK[r][0], wmc + (size_t)(i0 + r) * DH + c0);
        __syncthreads();   // all vc reads done before U overwrites v
#pragma unroll
        for (int r = 0; r < 4; r++) b8st(&accV[r][0], vc + (size_t)(i0 + r) * DH + c0);
    }
}

// ---------------------------------------------------------------------------
// MFMA inter-chunk scan (256 blocks = BH * 8 d-groups of 16).
// ---------------------------------------------------------------------------
__global__ __launch_bounds__(256) void scan_mfma(const u16* __restrict__ Wm,
                                                 const u16* __restrict__ U,
                                                 const u16* __restrict__ Qd,
                                                 const u16* __restrict__ Kd,
                                                 const u16* __restrict__ W2,
                                                 const float* __restrict__ gamC,
                                                 const float* __restrict__ S0,
                                                 float* __restrict__ Og,
                                                 float* __restrict__ Sfin) {
    __shared__ __align__(16) u16 sWm[64 * 136];
    __shared__ __align__(16) u16 sQd[64 * 136];
    __shared__ __align__(16) u16 sKdT[128 * 72];
    __shared__ __align__(16) u16 sW2[64 * 72];
    __shared__ __align__(16) u16 sS[16 * 136];
    __shared__ __align__(16) u16 sMidT[16 * 72];

    const int bid = blockIdx.x;
    const int bh = bid >> 3, dg = bid & 7, d0 = dg * 16;
    const int tid = threadIdx.x;
    const int w = tid >> 6, lane = tid & 63, lq = lane >> 4, ln = lane & 15;

    f32x4 S_t[2];
#pragma unroll
    for (int t2 = 0; t2 < 2; t2++)
#pragma unroll
        for (int r = 0; r < 4; r++)
            S_t[t2][r] = S0[(size_t)bh * DH * DH + (size_t)(d0 + lq * 4 + r) * DH + w * 32 + t2 * 16 + ln];

    for (int n = 0; n < NCH; n++) {
        const size_t cid = (size_t)bh * NCH + n;
        const u16* wmc = Wm + cid * CH * DH;
        const size_t tb = ((size_t)bh * L_ + (size_t)n * CH) * DH;
        const u16* uc = U + tb;
        const u16* qc = Qd + tb;
        const u16* kc = Kd + tb;
        const u16* w2c = W2 + cid * CH * CH;
        const float gC = gamC[cid];

#pragma unroll
        for (int t2 = 0; t2 < 2; t2++)
#pragma unroll
            for (int r = 0; r < 4; r++)
                sS[(lq * 4 + r) * 136 + w * 32 + t2 * 16 + ln] = f2b(S_t[t2][r]);

#pragma unroll
        for (int j = 0; j < 4; j++) {
            int f = tid + 256 * j;
            int row = f >> 4, kc8 = (f & 15) * 8;
            *(uint4*)&sWm[row * 136 + kc8] = *(const uint4*)(wmc + f * 8);
            *(uint4*)&sQd[row * 136 + kc8] = *(const uint4*)(qc + f * 8);
        }
#pragma unroll
        for (int j = 0; j < 2; j++) {
            int f = tid + 256 * j;
            int row = f >> 3, c8 = (f & 7) * 8;
            *(uint4*)&sW2[row * 72 + c8] = *(const uint4*)(w2c + f * 8);
        }
#pragma unroll
        for (int rep = 0; rep < 8; rep++) {
            int f = tid + 256 * rep;
            int i = f >> 5, e4 = (f & 31) * 4;
            ushort4 vv = *(const ushort4*)(kc + (size_t)f * 4);
            sKdT[(e4 + 0) * 72 + i] = vv.x;
            sKdT[(e4 + 1) * 72 + i] = vv.y;
            sKdT[(e4 + 2) * 72 + i] = vv.z;
            sKdT[(e4 + 3) * 72 + i] = vv.w;
        }
        __syncthreads();

        // G1: mid = U - Wm @ S^T
        f32x4 macc = (f32x4){0.f, 0.f, 0.f, 0.f};
#pragma unroll
        for (int ks = 0; ks < 4; ks++) {
            bf16x8 a = *(const bf16x8*)&sWm[(w * 16 + ln) * 136 + ks * 32 + lq * 8];
            bf16x8 b = *(const bf16x8*)&sS[ln * 136 + ks * 32 + lq * 8];
            macc = MFMA16(a, b, macc);
        }
#pragma unroll
        for (int r = 0; r < 4; r++) {
            int i = w * 16 + lq * 4 + r;
            float mv = b2f(uc[(size_t)i * DH + d0 + ln]) - macc[r];
            sMidT[ln * 72 + i] = f2b(mv);
        }
        __syncthreads();

        // G2: O = Qd @ S^T + W2 @ mid
        f32x4 oacc = (f32x4){0.f, 0.f, 0.f, 0.f};
#pragma unroll
        for (int ks = 0; ks < 4; ks++) {
            bf16x8 a = *(const bf16x8*)&sQd[(w * 16 + ln) * 136 + ks * 32 + lq * 8];
            bf16x8 b = *(const bf16x8*)&sS[ln * 136 + ks * 32 + lq * 8];
            oacc = MFMA16(a, b, oacc);
        }
#pragma unroll
        for (int ks = 0; ks < 2; ks++) {
            bf16x8 a = *(const bf16x8*)&sW2[(w * 16 + ln) * 72 + ks * 32 + lq * 8];
            bf16x8 b = *(const bf16x8*)&sMidT[ln * 72 + ks * 32 + lq * 8];
            oacc = MFMA16(a, b, oacc);
        }
#pragma unroll
        for (int r = 0; r < 4; r++) {
            int i = w * 16 + lq * 4 + r;
            Og[((size_t)bh * L_ + (size_t)n * CH + i) * DH + d0 + ln] = oacc[r];
        }

        // G3: S = gC*S + mid^T @ Kd
#pragma unroll
        for (int t2 = 0; t2 < 2; t2++)
#pragma unroll
            for (int r = 0; r < 4; r++) S_t[t2][r] *= gC;
#pragma unroll
        for (int ks = 0; ks < 2; ks++) {
            bf16x8 a = *(const bf16x8*)&sMidT[ln * 72 + ks * 32 + lq * 8];
#pragma unroll
            for (int t2 = 0; t2 < 2; t2++) {
                bf16x8 b = *(const bf16x8*)&sKdT[((2 * w + t2) * 16 + ln) * 72 + ks * 32 + lq * 8];
                S_t[t2] = MFMA16(a, b, S_t[t2]);
            }
        }
        __syncthreads();
    }

#pragma unroll
    for (int t2 = 0; t2 < 2; t2++)
#pragma unroll
        for (int r = 0; r < 4; r++)
            Sfin[(size_t)bh * DH * DH + (size_t)(d0 + lq * 4 + r) * DH + w * 32 + t2 * 16 + ln] = S_t[t2][r];
}

__global__ __launch_bounds__(256) void epilogue_gate(const float* __restrict__ Ob,
                                                     const u16* __restrict__ gpre,
                                                     const float* __restrict__ norm_w,
                                                     u16* __restrict__ gated) {
    int wid = blockIdx.x * 4 + (threadIdx.x >> 6);
    int lane = threadIdx.x & 63;
    int l = wid & (L_ - 1);
    int bh = wid >> 12;
    int b = bh >> 4, h = bh & 15;
    const float* orow = Ob + ((size_t)bh * L_ + l) * DH;
    float o0 = orow[lane], o1 = orow[lane + 64];
    float ss = o0 * o0 + o1 * o1;
#pragma unroll
    for (int m = 32; m >= 1; m >>= 1) ss += __shfl_xor(ss, m, 64);
    float r = rsqrtf(ss * (1.0f / 128.0f) + 1e-5f);
    size_t gidx = ((size_t)b * L_ + l) * HD + h * DH;
    float gp0 = b2f(gpre[gidx + lane]), gp1 = b2f(gpre[gidx + lane + 64]);
    gated[gidx + lane] = f2b(o0 * r * norm_w[lane] * (gp0 * sigm(gp0)));
    gated[gidx + lane + 64] = f2b(o1 * r * norm_w[lane + 64] * (gp1 * sigm(gp1)));
}

// ---------------------------------------------------------------------------
extern "C" void kernel_launch(void* const* d_in, const int* in_sizes, int n_in,
                              void* d_out, int out_size, void* d_ws, size_t ws_size,
                              hipStream_t stream) {
    const float* x       = (const float*)d_in[0];
    const float* Wq      = (const float*)d_in[1];
    const float* Wk      = (const float*)d_in[2];
    const float* Wv      = (const float*)d_in[3];
    const float* Wb      = (const float*)d_in[4];
    const float* Wa      = (const float*)d_in[5];
    const float* A_log   = (const float*)d_in[6];
    const float* dt_bias = (const float*)d_in[7];
    const float* conv_q  = (const float*)d_in[8];
    const float* conv_k  = (const float*)d_in[9];
    const float* conv_v  = (const float*)d_in[10];
    const float* Wg      = (const float*)d_in[11];
    const float* norm_w  = (const float*)d_in[12];
    const float* Wo      = (const float*)d_in[13];
    const float* S0      = (const float*)d_in[14];
    float* out = (float*)d_out;

    // Workspace (~195 MB, u16 units):
    //   Pb (preact scratch -> Wm), Qb (q->Qd), Kb (k->Kd -> gated),
    //   Vb (v->U -> gpre), W2b, xb (bf16 x), wbuf (rotating bf16 weight).
    // O (fp32) lives in d_out[0:PSZ]; Sfin in d_out[PSZ:].
    u16* Pb = (u16*)d_ws;
    u16* Qb = Pb + PSZ;
    u16* Kb = Qb + PSZ;
    u16* Vb = Kb + PSZ;
    u16* W2b = Vb + PSZ;                        // PSZ/2 u16
    u16* xb  = W2b + PSZ / 2;                   // PSZ u16
    u16* wbuf = xb + PSZ;                       // 2048*2048 u16
    float* bpre = (float*)(wbuf + 4194304);
    float* apre = bpre + BHL;
    float* betab = apre + BHL;
    float* gbuf = betab + BHL;
    float* gamC = gbuf + BHL;                   // 2048

    float* Obuf = out;
    float* Sfin = out + PSZ;

    dim3 gblk(16, 64);  // (N/128, M/128) for M=8192,N=2048
    const int W8 = 2048 * 2048 / 8;             // weight cvt groups

    cvt_f2b<<<8192, 256, 0, stream>>>(x, xb, (int)(PSZ / 8));
    cvt_f2b<<<2048, 256, 0, stream>>>(Wq, wbuf, W8);
    gemm_bt_async<u16><<<gblk, 256, 0, stream>>>(xb, wbuf, Pb, 8192, 2048, 2048);
    conv_silu_norm<<<32768, 256, 0, stream>>>(Pb, conv_q, Qb, 0);
    cvt_f2b<<<2048, 256, 0, stream>>>(Wk, wbuf, W8);
    gemm_bt_async<u16><<<gblk, 256, 0, stream>>>(xb, wbuf, Pb, 8192, 2048, 2048);
    conv_silu_norm<<<32768, 256, 0, stream>>>(Pb, conv_k, Kb, 1);
    cvt_f2b<<<2048, 256, 0, stream>>>(Wv, wbuf, W8);
    gemm_bt_async<u16><<<gblk, 256, 0, stream>>>(xb, wbuf, Pb, 8192, 2048, 2048);
    conv_silu_norm<<<32768, 256, 0, stream>>>(Pb, conv_v, Vb, 2);
    proj_small<<<8192, 64, 0, stream>>>(x, Wb, Wa, bpre, apre);
    beta_g_k<<<512, 256, 0, stream>>>(bpre, apre, A_log, dt_bias, betab, gbuf);
    prep_chunks<<<2048, 256, 0, stream>>>(Qb, Kb, Vb, betab, gbuf, Pb, W2b, gamC);
    scan_mfma<<<256, 256, 0, stream>>>(Pb, Vb, Qb, Kb, W2b, gamC, S0, Obuf, Sfin);
    // g projection after the scan: gpre reuses Vb (U is dead now)
    cvt_f2b<<<2048, 256, 0, stream>>>(Wg, wbuf, W8);
    gemm_bt_async<u16><<<gblk, 256, 0, stream>>>(xb, wbuf, Vb, 8192, 2048, 2048);
    epilogue_gate<<<32768, 256, 0, stream>>>(Obuf, Vb, norm_w, Kb);
    cvt_f2b<<<2048, 256, 0, stream>>>(Wo, wbuf, W8);
    gemm_bt_async<float><<<gblk, 256, 0, stream>>>(Kb, wbuf, out, 8192, 2048, 2048);
}